// Round 8
// baseline (345.567 us; speedup 1.0000x reference)
//
#include <hip/hip_runtime.h>

// Problem constants
#define NND   2048   // nodes
#define NC    64     // channels
#define NI    16     // irreps feat dim
#define NE    10     // elements
#define NT3   816    // sorted triples C(18,3) over 16 feats (i<=j<=l)
#define NT2   136    // sorted pairs
#define NPAD  1024   // padded term count: 816 triples + 136 pairs + 16 singles + 56 pad
#define CHUNK 16     // nodes per workgroup (16 -> ~30KB LDS -> 5 blocks/CU)
#define MAXIT 138    // max work items: 2048/16 + 10
#define M2ST  20     // sM2/sxT row stride in floats (16B-aligned, bank-spread)

// ws layout (bytes)
#define OFF_U3S   0u         // 4*816 float4   = 52224
#define OFF_U2S   52224u     // 4*136 float2   = 4352
#define OFF_TBL2  56576u     // 1024 int       = 4096
#define OFF_PTBL  60672u     // 136 int (pad)  = 576
#define OFF_NLIST 61248u     // 2048 int       = 8192
#define OFF_BST   69440u     // 16 int         = 64
#define OFF_ITEMS 69504u     // 160 int        = 640
#define OFF_NIT   70144u     // 16 int         = 64
#define OFF_F     70208u     // 2048*64 float4 = 2097152  (70208 = 16*4388)
#define OFF_S     2167360u   // 10*64*1024 float4 = 10485760
#define WS_NEED   12653120u  // ws_size >= this enables the precomputed-S path

// ---------------------------------------------------------------------------
__device__ inline void unrank3(int p, int& i, int& j, int& l) {
  int rem = p, i_ = 0;
  for (;;) { int cnt = (16 - i_) * (17 - i_) / 2; if (rem < cnt) break; rem -= cnt; ++i_; }
  int j_ = i_;
  for (;;) { int cnt = 16 - j_; if (rem < cnt) break; rem -= cnt; ++j_; }
  i = i_; j = j_; l = j_ + rem;
}
__device__ inline void unrank2(int q, int& i, int& j) {
  int rem = q, i_ = 0;
  for (;;) { int cnt = 16 - i_; if (rem < cnt) break; rem -= cnt; ++i_; }
  i = i_; j = i_ + rem;
}
__device__ inline int rank2(int a, int b) { return a * 16 - (a * (a - 1)) / 2 + (b - a); }

__device__ inline float4 u3read(const float* U3, int m, int a, int b, int d) {
  return *(const float4*)(U3 + (size_t)((((m * 16 + a) * 16 + b) * 16 + d) * 4));
}
__device__ inline float4 f4mul(float4 a, float4 b) {
  return make_float4(a.x * b.x, a.y * b.y, a.z * b.z, a.w * b.w);
}

// ---------------------------------------------------------------------------
// k_prep: block 0 = tbl2 + ptbl + U2sym; block 1 = element buckets;
// blocks 2..14 = U3sym (symmetrized cubic tensor).
__global__ __launch_bounds__(256) void k_prep(
    const float* __restrict__ U3_0, const float* __restrict__ U3_1,
    const float* __restrict__ U2_0, const float* __restrict__ U2_1,
    const float* __restrict__ y,
    float* __restrict__ U3sym, float* __restrict__ U2sym,
    int* __restrict__ tbl2, int* __restrict__ ptbl, int* __restrict__ nlist,
    int* __restrict__ bstart, int* __restrict__ items, int* __restrict__ nitems) {
  int tid = threadIdx.x;
  int bid = blockIdx.x;
  if (bid == 0) {
    // tbl2[p] = a | (qq<<8): monomial(p, node r) = sxT[a][r] * sM2[qq][r]
    for (int p = tid; p < NPAD; p += 256) {
      int a, qq;
      if (p < NT3) {
        int i, j, l; unrank3(p, i, j, l);
        a = l; qq = rank2(i, j);
      } else if (p < NT3 + NT2) {
        a = 16; qq = p - NT3;                 // pair: 1 * M2[q]
      } else if (p < NT3 + NT2 + 16) {
        a = 16; qq = 136 + (p - NT3 - NT2);   // single: 1 * x_i
      } else {
        a = 16; qq = 152;                     // pad: 1 * 0
      }
      tbl2[p] = a | (qq << 8);
    }
    for (int q = tid; q < NT2; q += 256) {
      int i, j; unrank2(q, i, j);
      ptbl[q] = i | (j << 8);
    }
    // U2sym[m4][q] = U2[m][i][j] + (i!=j ? U2[m][j][i] : 0)
    for (int idx = tid; idx < 4 * NT2; idx += 256) {
      int m4 = idx / NT2, q = idx - m4 * NT2;
      const float* U2 = (m4 == 0) ? U2_0 : U2_1;
      int mloc = (m4 == 0) ? 0 : (m4 - 1);
      int i, j; unrank2(q, i, j);
      const float* ua = U2 + (size_t)(((mloc * 16 + i) * 16 + j) * 2);
      float s0 = ua[0], s1 = ua[1];
      if (i != j) {
        const float* ub = U2 + (size_t)(((mloc * 16 + j) * 16 + i) * 2);
        s0 += ub[0]; s1 += ub[1];
      }
      float* o = U2sym + (size_t)(m4 * NT2 + q) * 2;
      o[0] = s0; o[1] = s1;
    }
  } else if (bid == 1) {
    // Bucket nodes by element (node_attrs is exact one-hot).
    __shared__ int cnt[NE], cur[NE];
    if (tid < NE) cnt[tid] = 0;
    __syncthreads();
    int mye[NND / 256];
    for (int rr = 0; rr < NND / 256; ++rr) {
      int b = tid + rr * 256;
      int e = 0;
      for (int ee = 0; ee < NE; ++ee)
        if (y[b * NE + ee] > 0.5f) e = ee;
      mye[rr] = e;
      atomicAdd(&cnt[e], 1);
    }
    __syncthreads();
    if (tid == 0) {
      int run = 0, ni = 0;
      for (int e = 0; e < NE; ++e) {
        bstart[e] = run; cur[e] = run;
        int nchunks = (cnt[e] + CHUNK - 1) / CHUNK;
        for (int ch = 0; ch < nchunks; ++ch) items[ni++] = e | (ch << 4);
        run += cnt[e];
      }
      bstart[NE] = run;
      nitems[0] = ni;
    }
    __syncthreads();
    for (int rr = 0; rr < NND / 256; ++rr) {
      int b = tid + rr * 256;
      int pos = atomicAdd(&cur[mye[rr]], 1);
      nlist[pos] = b;
    }
  } else {
    // U3sym[m4][tau] = sum over distinct perms of (i<=j<=l) of U3[m][a][b][d][:]
    int idx = (bid - 2) * 256 + tid;
    if (idx < 4 * NT3) {
      int m4 = idx / NT3, tau = idx - m4 * NT3;
      const float* U3 = (m4 == 0) ? U3_0 : U3_1;
      int mloc = (m4 == 0) ? 0 : (m4 - 1);
      int i, j, l; unrank3(tau, i, j, l);
      float4 s = u3read(U3, mloc, i, j, l);
      if (i == j && j == l) {
      } else if (i == j) {
        float4 b1 = u3read(U3, mloc, i, l, i), b2 = u3read(U3, mloc, l, i, i);
        s.x += b1.x + b2.x; s.y += b1.y + b2.y; s.z += b1.z + b2.z; s.w += b1.w + b2.w;
      } else if (j == l) {
        float4 b1 = u3read(U3, mloc, j, i, j), b2 = u3read(U3, mloc, j, j, i);
        s.x += b1.x + b2.x; s.y += b1.y + b2.y; s.z += b1.z + b2.z; s.w += b1.w + b2.w;
      } else {
        float4 b1 = u3read(U3, mloc, i, l, j), b2 = u3read(U3, mloc, j, i, l);
        float4 b3 = u3read(U3, mloc, j, l, i), b4 = u3read(U3, mloc, l, i, j);
        float4 b5 = u3read(U3, mloc, l, j, i);
        s.x += b1.x + b2.x + b3.x + b4.x + b5.x;
        s.y += b1.y + b2.y + b3.y + b4.y + b5.y;
        s.z += b1.z + b2.z + b3.z + b4.z + b5.z;
        s.w += b1.w + b2.w + b3.w + b4.w + b5.w;
      }
      ((float4*)U3sym)[m4 * NT3 + tau] = s;
    }
  }
}

// ---------------------------------------------------------------------------
// k_buildS: S[e][c][p][m4] = sym(U)[m4][p] . W[e,:,c]  (10.5 MB, L3-resident)
__global__ __launch_bounds__(256) void k_buildS(
    const float* __restrict__ U3sym, const float* __restrict__ U2sym,
    const float* __restrict__ U1_0, const float* __restrict__ U1_1,
    const float* __restrict__ W3_0, const float* __restrict__ W3_1,
    const float* __restrict__ W2_0, const float* __restrict__ W2_1,
    const float* __restrict__ W1_0, const float* __restrict__ W1_1,
    float* __restrict__ S) {
  int e = blockIdx.x, c = blockIdx.y, tid = threadIdx.x;
  float w30[4], w31[4], w20[2], w21[2];
#pragma unroll
  for (int k = 0; k < 4; ++k) {
    w30[k] = W3_0[e * 256 + k * 64 + c];
    w31[k] = W3_1[e * 256 + k * 64 + c];
  }
#pragma unroll
  for (int k = 0; k < 2; ++k) {
    w20[k] = W2_0[e * 128 + k * 64 + c];
    w21[k] = W2_1[e * 128 + k * 64 + c];
  }
  float w10 = W1_0[e * 64 + c], w11 = W1_1[e * 64 + c];
  const float4* U3s4 = (const float4*)U3sym;
  float4* Sg = (float4*)S + (size_t)(e * 64 + c) * NPAD;
#pragma unroll
  for (int k = 0; k < 4; ++k) {
    int p = tid + (k << 8);
    float4 o = make_float4(0.f, 0.f, 0.f, 0.f);
    if (p < NT3) {
      float4 u0 = U3s4[p];
      float4 u1 = U3s4[NT3 + p];
      float4 u2 = U3s4[2 * NT3 + p];
      float4 u3 = U3s4[3 * NT3 + p];
      o.x = u0.x * w30[0] + u0.y * w30[1] + u0.z * w30[2] + u0.w * w30[3];
      o.y = u1.x * w31[0] + u1.y * w31[1] + u1.z * w31[2] + u1.w * w31[3];
      o.z = u2.x * w31[0] + u2.y * w31[1] + u2.z * w31[2] + u2.w * w31[3];
      o.w = u3.x * w31[0] + u3.y * w31[1] + u3.z * w31[2] + u3.w * w31[3];
    } else if (p < NT3 + NT2) {
      int q = p - NT3;
      const float* u0 = U2sym + (size_t)(0 * NT2 + q) * 2;
      const float* u1 = U2sym + (size_t)(1 * NT2 + q) * 2;
      const float* u2 = U2sym + (size_t)(2 * NT2 + q) * 2;
      const float* u3 = U2sym + (size_t)(3 * NT2 + q) * 2;
      o.x = u0[0] * w20[0] + u0[1] * w20[1];
      o.y = u1[0] * w21[0] + u1[1] * w21[1];
      o.z = u2[0] * w21[0] + u2[1] * w21[1];
      o.w = u3[0] * w21[0] + u3[1] * w21[1];
    } else if (p < NT3 + NT2 + 16) {
      int i = p - NT3 - NT2;
      o.x = U1_0[i] * w10;
      o.y = U1_1[i] * w11;
      o.z = U1_1[16 + i] * w11;
      o.w = U1_1[32 + i] * w11;
    }
    Sg[p] = o;
  }
}

// ---------------------------------------------------------------------------
// merge two butterfly streams over lane-bit m.
__device__ inline float4 mergef4(float4 x, float4 y, int m, int lane) {
  float4 r;
  bool hi = (lane & m) != 0;
  { float t = x.x + __shfl_xor(x.x, m); float u = y.x + __shfl_xor(y.x, m); r.x = hi ? u : t; }
  { float t = x.y + __shfl_xor(x.y, m); float u = y.y + __shfl_xor(y.y, m); r.y = hi ? u : t; }
  { float t = x.z + __shfl_xor(x.z, m); float u = y.z + __shfl_xor(y.z, m); r.z = hi ? u : t; }
  { float t = x.w + __shfl_xor(x.w, m); float u = y.w + __shfl_xor(y.w, m); r.w = hi ? u : t; }
  return r;
}

// ---------------------------------------------------------------------------
// Main: block = (bucket chunk of 16 nodes, channel c). Wave w owns nodes
// 4w..4w+3; per-term gathers are one b128 per operand row. S tile comes from
// the precomputed global S (useS) or is rebuilt from U tables (fallback).
__global__ __launch_bounds__(256, 5) void k_main(
    const float* __restrict__ x, const float* __restrict__ Sglob, int useS,
    const float* __restrict__ U3sym, const float* __restrict__ U2sym,
    const float* __restrict__ U1_0, const float* __restrict__ U1_1,
    const float* __restrict__ W3_0, const float* __restrict__ W3_1,
    const float* __restrict__ W2_0, const float* __restrict__ W2_1,
    const float* __restrict__ W1_0, const float* __restrict__ W1_1,
    const int* __restrict__ tbl2, const int* __restrict__ ptbl,
    const int* __restrict__ nlist, const int* __restrict__ bstart,
    const int* __restrict__ items, const int* __restrict__ nitems,
    float* __restrict__ f) {
  int bx = blockIdx.x;
  if (bx >= nitems[0]) return;
  __shared__ __align__(16) float4 sS4[NPAD];        // 16 KB  [p] -> (m4=0..3)
  __shared__ __align__(16) float  sM2[153 * M2ST];  // 12.2 KB [qq][r], stride 20
  __shared__ __align__(16) float  sxT[17 * M2ST];   // 1.4 KB  [i][r], row16=1.0
  int tid = threadIdx.x;
  int w = tid >> 6, lane = tid & 63;
  int item = items[bx];
  int e = item & 15, ch = item >> 4;
  int c = blockIdx.y;
  int bs = bstart[e], be = bstart[e + 1];
  int base = bs + ch * CHUNK;
  int n_here = be - base; if (n_here > CHUNK) n_here = CHUNK;

  // Term codes -> registers (coalesced L2-resident loads, frees LDS pipe).
  int t2r[16];
#pragma unroll
  for (int q = 0; q < 16; ++q) t2r[q] = tbl2[lane + (q << 6)];

  // S tile: thread tid handles p = tid + 256k = p(lane, q=w+4k) for its own
  // wave -> register copy serves 4 of the 16 q-iterations.
  float4 sreg[4];
  if (useS) {
    const float4* Sg = (const float4*)Sglob + (size_t)(e * 64 + c) * NPAD;
#pragma unroll
    for (int k = 0; k < 4; ++k) {
      int p = tid + (k << 8);
      float4 o = Sg[p];
      sS4[p] = o;
      sreg[k] = o;
    }
  } else {
    float w30[4], w31[4], w20[2], w21[2];
#pragma unroll
    for (int k = 0; k < 4; ++k) {
      w30[k] = W3_0[e * 256 + k * 64 + c];
      w31[k] = W3_1[e * 256 + k * 64 + c];
    }
#pragma unroll
    for (int k = 0; k < 2; ++k) {
      w20[k] = W2_0[e * 128 + k * 64 + c];
      w21[k] = W2_1[e * 128 + k * 64 + c];
    }
    float w10 = W1_0[e * 64 + c], w11 = W1_1[e * 64 + c];
    const float4* U3s4 = (const float4*)U3sym;
#pragma unroll
    for (int k = 0; k < 4; ++k) {
      int p = tid + (k << 8);
      float4 o = make_float4(0.f, 0.f, 0.f, 0.f);
      if (p < NT3) {
        float4 u0 = U3s4[p];
        float4 u1 = U3s4[NT3 + p];
        float4 u2 = U3s4[2 * NT3 + p];
        float4 u3 = U3s4[3 * NT3 + p];
        o.x = u0.x * w30[0] + u0.y * w30[1] + u0.z * w30[2] + u0.w * w30[3];
        o.y = u1.x * w31[0] + u1.y * w31[1] + u1.z * w31[2] + u1.w * w31[3];
        o.z = u2.x * w31[0] + u2.y * w31[1] + u2.z * w31[2] + u2.w * w31[3];
        o.w = u3.x * w31[0] + u3.y * w31[1] + u3.z * w31[2] + u3.w * w31[3];
      } else if (p < NT3 + NT2) {
        int q = p - NT3;
        const float* u0 = U2sym + (size_t)(0 * NT2 + q) * 2;
        const float* u1 = U2sym + (size_t)(1 * NT2 + q) * 2;
        const float* u2 = U2sym + (size_t)(2 * NT2 + q) * 2;
        const float* u3 = U2sym + (size_t)(3 * NT2 + q) * 2;
        o.x = u0[0] * w20[0] + u0[1] * w20[1];
        o.y = u1[0] * w21[0] + u1[1] * w21[1];
        o.z = u2[0] * w21[0] + u2[1] * w21[1];
        o.w = u3[0] * w21[0] + u3[1] * w21[1];
      } else if (p < NT3 + NT2 + 16) {
        int i = p - NT3 - NT2;
        o.x = U1_0[i] * w10;
        o.y = U1_1[i] * w11;
        o.z = U1_1[16 + i] * w11;
        o.w = U1_1[32 + i] * w11;
      }
      sS4[p] = o;
      sreg[k] = o;
    }
  }
  // x tile, transposed: sxT[i][r] for 16 nodes; row 16 = constant 1.0.
  {
    int r = tid >> 4, i = tid & 15;
    float v = 0.f;
    if (r < n_here) {
      int b = nlist[base + r];
      v = x[(size_t)b * (NC * NI) + c * NI + i];
    }
    sxT[i * M2ST + r] = v;
    if (tid < CHUNK) sxT[16 * M2ST + tid] = 1.0f;
  }
  __syncthreads();
  // M2[qq][r]: 136 pair products, 16 singles, 1 zero row; r-quads via b128.
  for (int idx = tid; idx < 153 * 4; idx += 256) {
    int qq = idx >> 2, rq = (idx & 3) << 2;
    float4 v;
    if (qq < NT2) {
      int pv = ptbl[qq];
      float4 xi = *(const float4*)&sxT[(pv & 255) * M2ST + rq];
      float4 xj = *(const float4*)&sxT[(pv >> 8) * M2ST + rq];
      v = f4mul(xi, xj);
    } else if (qq < 152) {
      v = *(const float4*)&sxT[(qq - 136) * M2ST + rq];
    } else {
      v = make_float4(0.f, 0.f, 0.f, 0.f);
    }
    *(float4*)&sM2[qq * M2ST + rq] = v;
  }
  __syncthreads();

  float4 acc[4];
#pragma unroll
  for (int t = 0; t < 4; ++t) acc[t] = make_float4(0.f, 0.f, 0.f, 0.f);
  int rbase = 4 * w;
#pragma unroll
  for (int q = 0; q < 16; ++q) {       // full unroll: q compile-time for sreg/t2r
    int t2 = t2r[q];
    int ai = t2 & 255, qq = t2 >> 8;
    float4 xa = *(const float4*)&sxT[ai * M2ST + rbase];
    float4 ma = *(const float4*)&sM2[qq * M2ST + rbase];
    float4 sv;
    if ((q & 3) == w) sv = sreg[q >> 2];   // wave-uniform branch, skips ds_read
    else              sv = sS4[lane + (q << 6)];
    float mo[4];
    mo[0] = xa.x * ma.x; mo[1] = xa.y * ma.y; mo[2] = xa.z * ma.z; mo[3] = xa.w * ma.w;
#pragma unroll
    for (int t = 0; t < 4; ++t) {
      acc[t].x = fmaf(sv.x, mo[t], acc[t].x);
      acc[t].y = fmaf(sv.y, mo[t], acc[t].y);
      acc[t].z = fmaf(sv.z, mo[t], acc[t].z);
      acc[t].w = fmaf(sv.w, mo[t], acc[t].w);
    }
  }
  // Merge-tree reduction: 4 streams x float4 over 64 lanes (40 shfl).
  float4 s01 = mergef4(acc[0], acc[1], 32, lane);
  float4 s23 = mergef4(acc[2], acc[3], 32, lane);
  float4 u = mergef4(s01, s23, 16, lane);
#pragma unroll
  for (int m = 8; m >= 1; m >>= 1) {
    u.x += __shfl_xor(u.x, m);
    u.y += __shfl_xor(u.y, m);
    u.z += __shfl_xor(u.z, m);
    u.w += __shfl_xor(u.w, m);
  }
  // lane l (l%16==0) holds stream k = bit5 | bit4<<1 -> node 4w+k
  if ((lane & 15) == 0) {
    int k = ((lane >> 5) & 1) | (((lane >> 4) & 1) << 1);
    int r = rbase + k;
    if (r < n_here) {
      float4* fo = (float4*)f;
      fo[(size_t)nlist[base + r] * 64 + c] = u;
    }
  }
}

// ---------------------------------------------------------------------------
// Output: channel mix with Wlin (x 1/8), add sc. 4 nodes per block.
__global__ __launch_bounds__(256) void k_out(
    const float* __restrict__ f, const float* __restrict__ Wl0,
    const float* __restrict__ Wl1, const float* __restrict__ sc,
    float* __restrict__ out) {
  __shared__ float sW0[4096], sW1[4096], sf[4][256];
  int tid = threadIdx.x;
  for (int u = tid; u < 4096; u += 256) { sW0[u] = Wl0[u]; sW1[u] = Wl1[u]; }
  int nb = blockIdx.x * 4;
  for (int u = tid; u < 1024; u += 256) {
    int r = u >> 8, k = u & 255;
    sf[r][k] = f[(size_t)(nb + r) * 256 + k];
  }
  __syncthreads();
  int o = tid;
  int fch, msel; const float* Wl;
  if (o < 64) { fch = o; msel = 0; Wl = sW0; }
  else { int j = o - 64; fch = j / 3; msel = 1 + (j % 3); Wl = sW1; }
#pragma unroll
  for (int r = 0; r < 4; ++r) {
    float acc = 0.f;
#pragma unroll 8
    for (int cc = 0; cc < 64; ++cc)
      acc = fmaf(sf[r][cc * 4 + msel], Wl[cc * 64 + fch], acc);
    int b = nb + r;
    out[(size_t)b * 256 + o] = 0.125f * acc + sc[(size_t)b * 256 + o];
  }
}

// ---------------------------------------------------------------------------
extern "C" void kernel_launch(void* const* d_in, const int* in_sizes, int n_in,
                              void* d_out, int out_size, void* d_ws, size_t ws_size,
                              hipStream_t stream) {
  const float* node_feats = (const float*)d_in[0];
  const float* sc   = (const float*)d_in[1];
  const float* y    = (const float*)d_in[2];
  const float* U3_0 = (const float*)d_in[3];
  const float* U2_0 = (const float*)d_in[4];
  const float* U1_0 = (const float*)d_in[5];
  const float* W3_0 = (const float*)d_in[6];
  const float* W2_0 = (const float*)d_in[7];
  const float* W1_0 = (const float*)d_in[8];
  const float* Wl_0 = (const float*)d_in[9];
  const float* U3_1 = (const float*)d_in[10];
  const float* U2_1 = (const float*)d_in[11];
  const float* U1_1 = (const float*)d_in[12];
  const float* W3_1 = (const float*)d_in[13];
  const float* W2_1 = (const float*)d_in[14];
  const float* W1_1 = (const float*)d_in[15];
  const float* Wl_1 = (const float*)d_in[16];
  float* out = (float*)d_out;
  char* ws = (char*)d_ws;

  float* U3sym = (float*)(ws + OFF_U3S);
  float* U2sym = (float*)(ws + OFF_U2S);
  int*   tbl2  = (int*)(ws + OFF_TBL2);
  int*   ptbl  = (int*)(ws + OFF_PTBL);
  int*   nlist = (int*)(ws + OFF_NLIST);
  int*   bst   = (int*)(ws + OFF_BST);
  int*   items = (int*)(ws + OFF_ITEMS);
  int*   nit   = (int*)(ws + OFF_NIT);
  float* f     = (float*)(ws + OFF_F);
  float* S     = (float*)(ws + OFF_S);
  int useS = (ws_size >= (size_t)WS_NEED) ? 1 : 0;

  k_prep<<<15, 256, 0, stream>>>(U3_0, U3_1, U2_0, U2_1, y,
                                 U3sym, U2sym, tbl2, ptbl, nlist, bst, items, nit);
  if (useS) {
    k_buildS<<<dim3(NE, NC), 256, 0, stream>>>(U3sym, U2sym, U1_0, U1_1,
                                               W3_0, W3_1, W2_0, W2_1,
                                               W1_0, W1_1, S);
  }
  k_main<<<dim3(MAXIT, NC), 256, 0, stream>>>(node_feats, S, useS, U3sym, U2sym,
                                              U1_0, U1_1, W3_0, W3_1, W2_0, W2_1,
                                              W1_0, W1_1, tbl2, ptbl, nlist, bst,
                                              items, nit, f);
  k_out<<<NND / 4, 256, 0, stream>>>(f, Wl_0, Wl_1, sc, out);
}

// Round 9
// 186.248 us; speedup vs baseline: 1.8554x; 1.8554x over previous
//
#include <hip/hip_runtime.h>

// Problem constants
#define NND   2048   // nodes
#define NC    64     // channels
#define NI    16     // irreps feat dim
#define NE    10     // elements
#define NT3   816    // sorted triples C(18,3) over 16 feats (i<=j<=l)
#define NT2   136    // sorted pairs
#define NPAD  1024   // padded term count: 816 triples + 136 pairs + 16 singles + 56 pad
#define CHUNK 16     // nodes per workgroup (16 -> ~30KB LDS)
#define MAXIT 138    // max work items: 2048/16 + 10
#define M2ST  20     // sM2/sxT row stride in floats (16B-aligned, bank-spread)

// ws layout (bytes)
#define OFF_U3S   0u         // 4*816 float4   = 52224
#define OFF_U2S   52224u     // 4*136 float2   = 4352
#define OFF_TBL2  56576u     // 1024 int       = 4096
#define OFF_PTBL  60672u     // 136 int (pad)  = 576
#define OFF_NLIST 61248u     // 2048 int       = 8192
#define OFF_BST   69440u     // 16 int         = 64
#define OFF_ITEMS 69504u     // 160 int        = 640
#define OFF_NIT   70144u     // 16 int         = 64
#define OFF_F     70208u     // 2048*64 float4 = 2097152  (70208 = 16*4388)
#define OFF_S     2167360u   // 10*64*1024 float4 = 10485760
#define WS_NEED   12653120u  // ws_size >= this enables the precomputed-S path

// ---------------------------------------------------------------------------
__device__ inline void unrank3(int p, int& i, int& j, int& l) {
  int rem = p, i_ = 0;
  for (;;) { int cnt = (16 - i_) * (17 - i_) / 2; if (rem < cnt) break; rem -= cnt; ++i_; }
  int j_ = i_;
  for (;;) { int cnt = 16 - j_; if (rem < cnt) break; rem -= cnt; ++j_; }
  i = i_; j = j_; l = j_ + rem;
}
__device__ inline void unrank2(int q, int& i, int& j) {
  int rem = q, i_ = 0;
  for (;;) { int cnt = 16 - i_; if (rem < cnt) break; rem -= cnt; ++i_; }
  i = i_; j = i_ + rem;
}
__device__ inline int rank2(int a, int b) { return a * 16 - (a * (a - 1)) / 2 + (b - a); }

__device__ inline float4 u3read(const float* U3, int m, int a, int b, int d) {
  return *(const float4*)(U3 + (size_t)((((m * 16 + a) * 16 + b) * 16 + d) * 4));
}
__device__ inline float4 f4mul(float4 a, float4 b) {
  return make_float4(a.x * b.x, a.y * b.y, a.z * b.z, a.w * b.w);
}

// ---------------------------------------------------------------------------
// k_prep: block 0 = tbl2 + ptbl + U2sym; block 1 = element buckets;
// blocks 2..14 = U3sym (symmetrized cubic tensor).
__global__ __launch_bounds__(256) void k_prep(
    const float* __restrict__ U3_0, const float* __restrict__ U3_1,
    const float* __restrict__ U2_0, const float* __restrict__ U2_1,
    const float* __restrict__ y,
    float* __restrict__ U3sym, float* __restrict__ U2sym,
    int* __restrict__ tbl2, int* __restrict__ ptbl, int* __restrict__ nlist,
    int* __restrict__ bstart, int* __restrict__ items, int* __restrict__ nitems) {
  int tid = threadIdx.x;
  int bid = blockIdx.x;
  if (bid == 0) {
    // tbl2[p] = a | (qq<<8): monomial(p, node r) = sxT[a][r] * sM2[qq][r]
    for (int p = tid; p < NPAD; p += 256) {
      int a, qq;
      if (p < NT3) {
        int i, j, l; unrank3(p, i, j, l);
        a = l; qq = rank2(i, j);
      } else if (p < NT3 + NT2) {
        a = 16; qq = p - NT3;                 // pair: 1 * M2[q]
      } else if (p < NT3 + NT2 + 16) {
        a = 16; qq = 136 + (p - NT3 - NT2);   // single: 1 * x_i
      } else {
        a = 16; qq = 152;                     // pad: 1 * 0
      }
      tbl2[p] = a | (qq << 8);
    }
    for (int q = tid; q < NT2; q += 256) {
      int i, j; unrank2(q, i, j);
      ptbl[q] = i | (j << 8);
    }
    // U2sym[m4][q] = U2[m][i][j] + (i!=j ? U2[m][j][i] : 0)
    for (int idx = tid; idx < 4 * NT2; idx += 256) {
      int m4 = idx / NT2, q = idx - m4 * NT2;
      const float* U2 = (m4 == 0) ? U2_0 : U2_1;
      int mloc = (m4 == 0) ? 0 : (m4 - 1);
      int i, j; unrank2(q, i, j);
      const float* ua = U2 + (size_t)(((mloc * 16 + i) * 16 + j) * 2);
      float s0 = ua[0], s1 = ua[1];
      if (i != j) {
        const float* ub = U2 + (size_t)(((mloc * 16 + j) * 16 + i) * 2);
        s0 += ub[0]; s1 += ub[1];
      }
      float* o = U2sym + (size_t)(m4 * NT2 + q) * 2;
      o[0] = s0; o[1] = s1;
    }
  } else if (bid == 1) {
    // Bucket nodes by element (node_attrs is exact one-hot).
    __shared__ int cnt[NE], cur[NE];
    if (tid < NE) cnt[tid] = 0;
    __syncthreads();
    int mye[NND / 256];
    for (int rr = 0; rr < NND / 256; ++rr) {
      int b = tid + rr * 256;
      int e = 0;
      for (int ee = 0; ee < NE; ++ee)
        if (y[b * NE + ee] > 0.5f) e = ee;
      mye[rr] = e;
      atomicAdd(&cnt[e], 1);
    }
    __syncthreads();
    if (tid == 0) {
      int run = 0, ni = 0;
      for (int e = 0; e < NE; ++e) {
        bstart[e] = run; cur[e] = run;
        int nchunks = (cnt[e] + CHUNK - 1) / CHUNK;
        for (int ch = 0; ch < nchunks; ++ch) items[ni++] = e | (ch << 4);
        run += cnt[e];
      }
      bstart[NE] = run;
      nitems[0] = ni;
    }
    __syncthreads();
    for (int rr = 0; rr < NND / 256; ++rr) {
      int b = tid + rr * 256;
      int pos = atomicAdd(&cur[mye[rr]], 1);
      nlist[pos] = b;
    }
  } else {
    // U3sym[m4][tau] = sum over distinct perms of (i<=j<=l) of U3[m][a][b][d][:]
    int idx = (bid - 2) * 256 + tid;
    if (idx < 4 * NT3) {
      int m4 = idx / NT3, tau = idx - m4 * NT3;
      const float* U3 = (m4 == 0) ? U3_0 : U3_1;
      int mloc = (m4 == 0) ? 0 : (m4 - 1);
      int i, j, l; unrank3(tau, i, j, l);
      float4 s = u3read(U3, mloc, i, j, l);
      if (i == j && j == l) {
      } else if (i == j) {
        float4 b1 = u3read(U3, mloc, i, l, i), b2 = u3read(U3, mloc, l, i, i);
        s.x += b1.x + b2.x; s.y += b1.y + b2.y; s.z += b1.z + b2.z; s.w += b1.w + b2.w;
      } else if (j == l) {
        float4 b1 = u3read(U3, mloc, j, i, j), b2 = u3read(U3, mloc, j, j, i);
        s.x += b1.x + b2.x; s.y += b1.y + b2.y; s.z += b1.z + b2.z; s.w += b1.w + b2.w;
      } else {
        float4 b1 = u3read(U3, mloc, i, l, j), b2 = u3read(U3, mloc, j, i, l);
        float4 b3 = u3read(U3, mloc, j, l, i), b4 = u3read(U3, mloc, l, i, j);
        float4 b5 = u3read(U3, mloc, l, j, i);
        s.x += b1.x + b2.x + b3.x + b4.x + b5.x;
        s.y += b1.y + b2.y + b3.y + b4.y + b5.y;
        s.z += b1.z + b2.z + b3.z + b4.z + b5.z;
        s.w += b1.w + b2.w + b3.w + b4.w + b5.w;
      }
      ((float4*)U3sym)[m4 * NT3 + tau] = s;
    }
  }
}

// ---------------------------------------------------------------------------
// k_buildS: S[e][c][p][m4] = sym(U)[m4][p] . W[e,:,c]  (10.5 MB, L3-resident)
__global__ __launch_bounds__(256) void k_buildS(
    const float* __restrict__ U3sym, const float* __restrict__ U2sym,
    const float* __restrict__ U1_0, const float* __restrict__ U1_1,
    const float* __restrict__ W3_0, const float* __restrict__ W3_1,
    const float* __restrict__ W2_0, const float* __restrict__ W2_1,
    const float* __restrict__ W1_0, const float* __restrict__ W1_1,
    float* __restrict__ S) {
  int e = blockIdx.x, c = blockIdx.y, tid = threadIdx.x;
  float w30[4], w31[4], w20[2], w21[2];
#pragma unroll
  for (int k = 0; k < 4; ++k) {
    w30[k] = W3_0[e * 256 + k * 64 + c];
    w31[k] = W3_1[e * 256 + k * 64 + c];
  }
#pragma unroll
  for (int k = 0; k < 2; ++k) {
    w20[k] = W2_0[e * 128 + k * 64 + c];
    w21[k] = W2_1[e * 128 + k * 64 + c];
  }
  float w10 = W1_0[e * 64 + c], w11 = W1_1[e * 64 + c];
  const float4* U3s4 = (const float4*)U3sym;
  float4* Sg = (float4*)S + (size_t)(e * 64 + c) * NPAD;
#pragma unroll
  for (int k = 0; k < 4; ++k) {
    int p = tid + (k << 8);
    float4 o = make_float4(0.f, 0.f, 0.f, 0.f);
    if (p < NT3) {
      float4 u0 = U3s4[p];
      float4 u1 = U3s4[NT3 + p];
      float4 u2 = U3s4[2 * NT3 + p];
      float4 u3 = U3s4[3 * NT3 + p];
      o.x = u0.x * w30[0] + u0.y * w30[1] + u0.z * w30[2] + u0.w * w30[3];
      o.y = u1.x * w31[0] + u1.y * w31[1] + u1.z * w31[2] + u1.w * w31[3];
      o.z = u2.x * w31[0] + u2.y * w31[1] + u2.z * w31[2] + u2.w * w31[3];
      o.w = u3.x * w31[0] + u3.y * w31[1] + u3.z * w31[2] + u3.w * w31[3];
    } else if (p < NT3 + NT2) {
      int q = p - NT3;
      const float* u0 = U2sym + (size_t)(0 * NT2 + q) * 2;
      const float* u1 = U2sym + (size_t)(1 * NT2 + q) * 2;
      const float* u2 = U2sym + (size_t)(2 * NT2 + q) * 2;
      const float* u3 = U2sym + (size_t)(3 * NT2 + q) * 2;
      o.x = u0[0] * w20[0] + u0[1] * w20[1];
      o.y = u1[0] * w21[0] + u1[1] * w21[1];
      o.z = u2[0] * w21[0] + u2[1] * w21[1];
      o.w = u3[0] * w21[0] + u3[1] * w21[1];
    } else if (p < NT3 + NT2 + 16) {
      int i = p - NT3 - NT2;
      o.x = U1_0[i] * w10;
      o.y = U1_1[i] * w11;
      o.z = U1_1[16 + i] * w11;
      o.w = U1_1[32 + i] * w11;
    }
    Sg[p] = o;
  }
}

// ---------------------------------------------------------------------------
// merge two butterfly streams over lane-bit m.
__device__ inline float4 mergef4(float4 x, float4 y, int m, int lane) {
  float4 r;
  bool hi = (lane & m) != 0;
  { float t = x.x + __shfl_xor(x.x, m); float u = y.x + __shfl_xor(y.x, m); r.x = hi ? u : t; }
  { float t = x.y + __shfl_xor(x.y, m); float u = y.y + __shfl_xor(y.y, m); r.y = hi ? u : t; }
  { float t = x.z + __shfl_xor(x.z, m); float u = y.z + __shfl_xor(y.z, m); r.z = hi ? u : t; }
  { float t = x.w + __shfl_xor(x.w, m); float u = y.w + __shfl_xor(y.w, m); r.w = hi ? u : t; }
  return r;
}

// ---------------------------------------------------------------------------
// Main: block = (bucket chunk of 16 nodes, channel c). Wave w owns nodes
// 4w..4w+3; per-term gathers are one b128 per operand row. S tile comes from
// the precomputed global S (useS) or is rebuilt from U tables (fallback).
// NOTE: (256,4) not (256,5) — the 5-waves/EU cap forced VGPR=48 and spilled
// ~1 GB/dispatch to scratch (R8 post-mortem: FETCH 386MB/WRITE 600MB).
__global__ __launch_bounds__(256, 4) void k_main(
    const float* __restrict__ x, const float* __restrict__ Sglob, int useS,
    const float* __restrict__ U3sym, const float* __restrict__ U2sym,
    const float* __restrict__ U1_0, const float* __restrict__ U1_1,
    const float* __restrict__ W3_0, const float* __restrict__ W3_1,
    const float* __restrict__ W2_0, const float* __restrict__ W2_1,
    const float* __restrict__ W1_0, const float* __restrict__ W1_1,
    const int* __restrict__ tbl2, const int* __restrict__ ptbl,
    const int* __restrict__ nlist, const int* __restrict__ bstart,
    const int* __restrict__ items, const int* __restrict__ nitems,
    float* __restrict__ f) {
  int bx = blockIdx.x;
  if (bx >= nitems[0]) return;
  __shared__ __align__(16) float4 sS4[NPAD];        // 16 KB  [p] -> (m4=0..3)
  __shared__ __align__(16) float  sM2[153 * M2ST];  // 12.2 KB [qq][r], stride 20
  __shared__ __align__(16) float  sxT[17 * M2ST];   // 1.4 KB  [i][r], row16=1.0
  int tid = threadIdx.x;
  int w = tid >> 6, lane = tid & 63;
  int item = items[bx];
  int e = item & 15, ch = item >> 4;
  int c = blockIdx.y;
  int bs = bstart[e], be = bstart[e + 1];
  int base = bs + ch * CHUNK;
  int n_here = be - base; if (n_here > CHUNK) n_here = CHUNK;

  // Term codes -> registers (coalesced L2-resident loads, frees LDS pipe).
  int t2r[16];
#pragma unroll
  for (int q = 0; q < 16; ++q) t2r[q] = tbl2[lane + (q << 6)];

  // S tile: thread tid handles p = tid + 256k = p(lane, q=w+4k) for its own
  // wave -> register copy serves 4 of the 16 q-iterations.
  float4 sreg[4];
  if (useS) {
    const float4* Sg = (const float4*)Sglob + (size_t)(e * 64 + c) * NPAD;
#pragma unroll
    for (int k = 0; k < 4; ++k) {
      int p = tid + (k << 8);
      float4 o = Sg[p];
      sS4[p] = o;
      sreg[k] = o;
    }
  } else {
    float w30[4], w31[4], w20[2], w21[2];
#pragma unroll
    for (int k = 0; k < 4; ++k) {
      w30[k] = W3_0[e * 256 + k * 64 + c];
      w31[k] = W3_1[e * 256 + k * 64 + c];
    }
#pragma unroll
    for (int k = 0; k < 2; ++k) {
      w20[k] = W2_0[e * 128 + k * 64 + c];
      w21[k] = W2_1[e * 128 + k * 64 + c];
    }
    float w10 = W1_0[e * 64 + c], w11 = W1_1[e * 64 + c];
    const float4* U3s4 = (const float4*)U3sym;
#pragma unroll
    for (int k = 0; k < 4; ++k) {
      int p = tid + (k << 8);
      float4 o = make_float4(0.f, 0.f, 0.f, 0.f);
      if (p < NT3) {
        float4 u0 = U3s4[p];
        float4 u1 = U3s4[NT3 + p];
        float4 u2 = U3s4[2 * NT3 + p];
        float4 u3 = U3s4[3 * NT3 + p];
        o.x = u0.x * w30[0] + u0.y * w30[1] + u0.z * w30[2] + u0.w * w30[3];
        o.y = u1.x * w31[0] + u1.y * w31[1] + u1.z * w31[2] + u1.w * w31[3];
        o.z = u2.x * w31[0] + u2.y * w31[1] + u2.z * w31[2] + u2.w * w31[3];
        o.w = u3.x * w31[0] + u3.y * w31[1] + u3.z * w31[2] + u3.w * w31[3];
      } else if (p < NT3 + NT2) {
        int q = p - NT3;
        const float* u0 = U2sym + (size_t)(0 * NT2 + q) * 2;
        const float* u1 = U2sym + (size_t)(1 * NT2 + q) * 2;
        const float* u2 = U2sym + (size_t)(2 * NT2 + q) * 2;
        const float* u3 = U2sym + (size_t)(3 * NT2 + q) * 2;
        o.x = u0[0] * w20[0] + u0[1] * w20[1];
        o.y = u1[0] * w21[0] + u1[1] * w21[1];
        o.z = u2[0] * w21[0] + u2[1] * w21[1];
        o.w = u3[0] * w21[0] + u3[1] * w21[1];
      } else if (p < NT3 + NT2 + 16) {
        int i = p - NT3 - NT2;
        o.x = U1_0[i] * w10;
        o.y = U1_1[i] * w11;
        o.z = U1_1[16 + i] * w11;
        o.w = U1_1[32 + i] * w11;
      }
      sS4[p] = o;
      sreg[k] = o;
    }
  }
  // x tile, transposed: sxT[i][r] for 16 nodes; row 16 = constant 1.0.
  {
    int r = tid >> 4, i = tid & 15;
    float v = 0.f;
    if (r < n_here) {
      int b = nlist[base + r];
      v = x[(size_t)b * (NC * NI) + c * NI + i];
    }
    sxT[i * M2ST + r] = v;
    if (tid < CHUNK) sxT[16 * M2ST + tid] = 1.0f;
  }
  __syncthreads();
  // M2[qq][r]: 136 pair products, 16 singles, 1 zero row; r-quads via b128.
  for (int idx = tid; idx < 153 * 4; idx += 256) {
    int qq = idx >> 2, rq = (idx & 3) << 2;
    float4 v;
    if (qq < NT2) {
      int pv = ptbl[qq];
      float4 xi = *(const float4*)&sxT[(pv & 255) * M2ST + rq];
      float4 xj = *(const float4*)&sxT[(pv >> 8) * M2ST + rq];
      v = f4mul(xi, xj);
    } else if (qq < 152) {
      v = *(const float4*)&sxT[(qq - 136) * M2ST + rq];
    } else {
      v = make_float4(0.f, 0.f, 0.f, 0.f);
    }
    *(float4*)&sM2[qq * M2ST + rq] = v;
  }
  __syncthreads();

  float4 acc[4];
#pragma unroll
  for (int t = 0; t < 4; ++t) acc[t] = make_float4(0.f, 0.f, 0.f, 0.f);
  int rbase = 4 * w;
#pragma unroll
  for (int q = 0; q < 16; ++q) {       // full unroll: q compile-time for sreg/t2r
    int t2 = t2r[q];
    int ai = t2 & 255, qq = t2 >> 8;
    float4 xa = *(const float4*)&sxT[ai * M2ST + rbase];
    float4 ma = *(const float4*)&sM2[qq * M2ST + rbase];
    float4 sv;
    if ((q & 3) == w) sv = sreg[q >> 2];   // wave-uniform branch, skips ds_read
    else              sv = sS4[lane + (q << 6)];
    float mo[4];
    mo[0] = xa.x * ma.x; mo[1] = xa.y * ma.y; mo[2] = xa.z * ma.z; mo[3] = xa.w * ma.w;
#pragma unroll
    for (int t = 0; t < 4; ++t) {
      acc[t].x = fmaf(sv.x, mo[t], acc[t].x);
      acc[t].y = fmaf(sv.y, mo[t], acc[t].y);
      acc[t].z = fmaf(sv.z, mo[t], acc[t].z);
      acc[t].w = fmaf(sv.w, mo[t], acc[t].w);
    }
  }
  // Merge-tree reduction: 4 streams x float4 over 64 lanes (40 shfl).
  float4 s01 = mergef4(acc[0], acc[1], 32, lane);
  float4 s23 = mergef4(acc[2], acc[3], 32, lane);
  float4 u = mergef4(s01, s23, 16, lane);
#pragma unroll
  for (int m = 8; m >= 1; m >>= 1) {
    u.x += __shfl_xor(u.x, m);
    u.y += __shfl_xor(u.y, m);
    u.z += __shfl_xor(u.z, m);
    u.w += __shfl_xor(u.w, m);
  }
  // lane l (l%16==0) holds stream k = bit5 | bit4<<1 -> node 4w+k
  if ((lane & 15) == 0) {
    int k = ((lane >> 5) & 1) | (((lane >> 4) & 1) << 1);
    int r = rbase + k;
    if (r < n_here) {
      float4* fo = (float4*)f;
      fo[(size_t)nlist[base + r] * 64 + c] = u;
    }
  }
}

// ---------------------------------------------------------------------------
// Output: channel mix with Wlin (x 1/8), add sc. 4 nodes per block.
__global__ __launch_bounds__(256) void k_out(
    const float* __restrict__ f, const float* __restrict__ Wl0,
    const float* __restrict__ Wl1, const float* __restrict__ sc,
    float* __restrict__ out) {
  __shared__ float sW0[4096], sW1[4096], sf[4][256];
  int tid = threadIdx.x;
  for (int u = tid; u < 4096; u += 256) { sW0[u] = Wl0[u]; sW1[u] = Wl1[u]; }
  int nb = blockIdx.x * 4;
  for (int u = tid; u < 1024; u += 256) {
    int r = u >> 8, k = u & 255;
    sf[r][k] = f[(size_t)(nb + r) * 256 + k];
  }
  __syncthreads();
  int o = tid;
  int fch, msel; const float* Wl;
  if (o < 64) { fch = o; msel = 0; Wl = sW0; }
  else { int j = o - 64; fch = j / 3; msel = 1 + (j % 3); Wl = sW1; }
#pragma unroll
  for (int r = 0; r < 4; ++r) {
    float acc = 0.f;
#pragma unroll 8
    for (int cc = 0; cc < 64; ++cc)
      acc = fmaf(sf[r][cc * 4 + msel], Wl[cc * 64 + fch], acc);
    int b = nb + r;
    out[(size_t)b * 256 + o] = 0.125f * acc + sc[(size_t)b * 256 + o];
  }
}

// ---------------------------------------------------------------------------
extern "C" void kernel_launch(void* const* d_in, const int* in_sizes, int n_in,
                              void* d_out, int out_size, void* d_ws, size_t ws_size,
                              hipStream_t stream) {
  const float* node_feats = (const float*)d_in[0];
  const float* sc   = (const float*)d_in[1];
  const float* y    = (const float*)d_in[2];
  const float* U3_0 = (const float*)d_in[3];
  const float* U2_0 = (const float*)d_in[4];
  const float* U1_0 = (const float*)d_in[5];
  const float* W3_0 = (const float*)d_in[6];
  const float* W2_0 = (const float*)d_in[7];
  const float* W1_0 = (const float*)d_in[8];
  const float* Wl_0 = (const float*)d_in[9];
  const float* U3_1 = (const float*)d_in[10];
  const float* U2_1 = (const float*)d_in[11];
  const float* U1_1 = (const float*)d_in[12];
  const float* W3_1 = (const float*)d_in[13];
  const float* W2_1 = (const float*)d_in[14];
  const float* W1_1 = (const float*)d_in[15];
  const float* Wl_1 = (const float*)d_in[16];
  float* out = (float*)d_out;
  char* ws = (char*)d_ws;

  float* U3sym = (float*)(ws + OFF_U3S);
  float* U2sym = (float*)(ws + OFF_U2S);
  int*   tbl2  = (int*)(ws + OFF_TBL2);
  int*   ptbl  = (int*)(ws + OFF_PTBL);
  int*   nlist = (int*)(ws + OFF_NLIST);
  int*   bst   = (int*)(ws + OFF_BST);
  int*   items = (int*)(ws + OFF_ITEMS);
  int*   nit   = (int*)(ws + OFF_NIT);
  float* f     = (float*)(ws + OFF_F);
  float* S     = (float*)(ws + OFF_S);
  int useS = (ws_size >= (size_t)WS_NEED) ? 1 : 0;

  k_prep<<<15, 256, 0, stream>>>(U3_0, U3_1, U2_0, U2_1, y,
                                 U3sym, U2sym, tbl2, ptbl, nlist, bst, items, nit);
  if (useS) {
    k_buildS<<<dim3(NE, NC), 256, 0, stream>>>(U3sym, U2sym, U1_0, U1_1,
                                               W3_0, W3_1, W2_0, W2_1,
                                               W1_0, W1_1, S);
  }
  k_main<<<dim3(MAXIT, NC), 256, 0, stream>>>(node_feats, S, useS, U3sym, U2sym,
                                              U1_0, U1_1, W3_0, W3_1, W2_0, W2_1,
                                              W1_0, W1_1, tbl2, ptbl, nlist, bst,
                                              items, nit, f);
  k_out<<<NND / 4, 256, 0, stream>>>(f, Wl_0, Wl_1, sc, out);
}